// Round 2
// baseline (266.039 us; speedup 1.0000x reference)
//
#include <hip/hip_runtime.h>

#define N_NODES 10000
#define N_EDGES 320000
#define DIM 256

typedef _Float16 half8 __attribute__((ext_vector_type(8)));
typedef float floatx4 __attribute__((ext_vector_type(4)));

// ---------------- fp32 -> fp16 conversion ----------------
__device__ __forceinline__ half8 cvt8(const float4 a, const float4 b) {
  half8 o;
  o[0] = (_Float16)a.x; o[1] = (_Float16)a.y; o[2] = (_Float16)a.z; o[3] = (_Float16)a.w;
  o[4] = (_Float16)b.x; o[5] = (_Float16)b.y; o[6] = (_Float16)b.z; o[7] = (_Float16)b.w;
  return o;
}

__global__ void cvt_f2h(const float* __restrict__ in, _Float16* __restrict__ out, int n8) {
  int i = blockIdx.x * blockDim.x + threadIdx.x;
  if (i >= n8) return;
  const float4* p = (const float4*)in;
  ((half8*)out)[i] = cvt8(p[2 * i], p[2 * i + 1]);
}

// converts the four 256x256 weight matrices (65536 elems = 8192 half8 each)
__global__ void cvt4_f2h(const float* __restrict__ a0, const float* __restrict__ a1,
                         const float* __restrict__ a2, const float* __restrict__ a3,
                         _Float16* __restrict__ o0, _Float16* __restrict__ o1,
                         _Float16* __restrict__ o2, _Float16* __restrict__ o3) {
  int w = blockIdx.y;
  const float* in = (w == 0) ? a0 : (w == 1) ? a1 : (w == 2) ? a2 : a3;
  _Float16* out = (w == 0) ? o0 : (w == 1) ? o1 : (w == 2) ? o2 : o3;
  int i = blockIdx.x * blockDim.x + threadIdx.x;  // 0..8191
  const float4* p = (const float4*)in;
  ((half8*)out)[i] = cvt8(p[2 * i], p[2 * i + 1]);
}

// ---------------- fp16 MFMA GEMM: Y[M,256] = X[M,256] @ W[256,256]^T + b ----------------
// Wave computes a 16x64 tile. A-frag: lane holds X[m0+(lane&15)][k0+quad*8+j] (8 halves).
// B-frag: lane holds W[n0+t*16+(lane&15)][k0+quad*8+j]. C/D: col=lane&15, row=quad*4+reg.
template <typename OutT>
__device__ __forceinline__ void gemm_body(const _Float16* __restrict__ X,
                                          const _Float16* __restrict__ W,
                                          const float* __restrict__ bias,
                                          OutT* __restrict__ Y, int M) {
  int wid = threadIdx.x >> 6;
  int lane = threadIdx.x & 63;
  int quad = lane >> 4;
  int l16 = lane & 15;
  int m0 = blockIdx.x * 64 + wid * 16;
  int n0 = blockIdx.y * 64;
  int row = m0 + l16;
  int rowc = (row < M) ? row : (M - 1);
  const half8* Xr = (const half8*)(X + (size_t)rowc * DIM);

  floatx4 acc[4];
#pragma unroll
  for (int t = 0; t < 4; ++t) acc[t] = (floatx4){0.f, 0.f, 0.f, 0.f};

#pragma unroll
  for (int kk = 0; kk < 8; ++kk) {
    half8 a = Xr[kk * 4 + quad];
#pragma unroll
    for (int t = 0; t < 4; ++t) {
      const half8* Wr = (const half8*)(W + (size_t)(n0 + t * 16 + l16) * DIM);
      half8 b = Wr[kk * 4 + quad];
      acc[t] = __builtin_amdgcn_mfma_f32_16x16x32_f16(a, b, acc[t], 0, 0, 0);
    }
  }

#pragma unroll
  for (int t = 0; t < 4; ++t) {
    int col = n0 + t * 16 + l16;
    float bv = bias[col];
#pragma unroll
    for (int r = 0; r < 4; ++r) {
      int rr = m0 + quad * 4 + r;
      if (rr < M) {
        float val = acc[t][r] + bv;
        Y[(size_t)rr * DIM + col] = (OutT)val;
      }
    }
  }
}

__global__ void __launch_bounds__(256) gemm_qkv(
    const _Float16* __restrict__ xh,
    const _Float16* __restrict__ Wq, const _Float16* __restrict__ Wk,
    const _Float16* __restrict__ Wv,
    const float* __restrict__ bq, const float* __restrict__ bk,
    const float* __restrict__ bv,
    _Float16* __restrict__ q, _Float16* __restrict__ k, _Float16* __restrict__ v, int M) {
  int z = blockIdx.z;
  const _Float16* W = (z == 0) ? Wq : (z == 1) ? Wk : Wv;
  const float* b = (z == 0) ? bq : (z == 1) ? bk : bv;
  _Float16* Y = (z == 0) ? q : (z == 1) ? k : v;
  gemm_body<_Float16>(xh, W, b, Y, M);
}

__global__ void __launch_bounds__(256) gemm_out(
    const _Float16* __restrict__ hh, const _Float16* __restrict__ Wo,
    const float* __restrict__ bo, float* __restrict__ out, int M) {
  gemm_body<float>(hh, Wo, bo, out, M);
}

// ---------------- CSR build ----------------
__global__ void count_k(const int* __restrict__ dst, int* __restrict__ counts) {
  int e = blockIdx.x * blockDim.x + threadIdx.x;
  if (e < N_EDGES) atomicAdd(&counts[dst[e]], 1);
}

__global__ void scan_k(const int* __restrict__ counts, int* __restrict__ offs,
                       int* __restrict__ cursor) {
  __shared__ int ssum[256];
  int t = threadIdx.x;
  const int CH = 40;  // 256*40 = 10240 >= 10000
  int begin = t * CH;
  int end = begin + CH;
  if (end > N_NODES) end = N_NODES;
  int s = 0;
  for (int i = begin; i < end; ++i) s += counts[i];
  ssum[t] = s;
  __syncthreads();
  if (t == 0) {
    int run = 0;
    for (int i = 0; i < 256; ++i) {
      int c = ssum[i];
      ssum[i] = run;
      run += c;
    }
    offs[N_NODES] = run;  // == N_EDGES
  }
  __syncthreads();
  int run = ssum[t];
  for (int i = begin; i < end; ++i) {
    offs[i] = run;
    cursor[i] = run;
    run += counts[i];
  }
}

__global__ void scatter_k(const int* __restrict__ dst, int* __restrict__ cursor,
                          int* __restrict__ elist) {
  int e = blockIdx.x * blockDim.x + threadIdx.x;
  if (e < N_EDGES) {
    int pos = atomicAdd(&cursor[dst[e]], 1);
    elist[pos] = e;
  }
}

// ---------------- fused score+softmax+aggregate ----------------
// One wave per node. 32 lanes per edge (2 edges/iter). Lane l (within 32): dims
// (l&31)*8 .. +7, head = (l&31)>>2 (4 lanes x 8 dims = 32 dims/head).
// score[e,h] = dot(q[src,h,:], k[n,h,:]) / sqrt(32); softmax over the 8 heads;
// acc += v[src] * attn. Finally write h[n] as fp16.
__global__ void __launch_bounds__(256) aggregate_k(
    const _Float16* __restrict__ qh, const _Float16* __restrict__ kh,
    const _Float16* __restrict__ vh, const int* __restrict__ src,
    const int* __restrict__ elist, const int* __restrict__ offs,
    _Float16* __restrict__ hh) {
  int wid = threadIdx.x >> 6;
  int lane = threadIdx.x & 63;
  int n = blockIdx.x * 4 + wid;
  if (n >= N_NODES) return;
  int l32 = lane & 31;
  int hi = lane >> 5;  // which edge of the pair

  // k row of this node (8 halves per lane, dims l32*8..)
  half8 kv8 = ((const half8*)(kh + (size_t)n * DIM))[l32];
  float kf[8];
#pragma unroll
  for (int i = 0; i < 8; ++i) kf[i] = (float)kv8[i];

  float acc[8];
#pragma unroll
  for (int i = 0; i < 8; ++i) acc[i] = 0.f;

  const float scale = 0.17677669529663687f;  // 1/sqrt(32)
  int e0 = offs[n];
  int deg = offs[n + 1] - e0;

  for (int base = 0; base < deg; base += 64) {
    int nb = deg - base;
    if (nb > 64) nb = 64;
    int sid = 0;
    if (lane < nb) sid = src[elist[e0 + base + lane]];
    int pairs = (nb + 1) >> 1;
    for (int j = 0; j < pairs; ++j) {
      int idx = 2 * j + hi;
      bool valid = idx < nb;
      int s = __shfl(sid, idx);  // clamped lanes hold 0 -> safe row
      // score partial: q[s] . k[n] over this lane's 8 dims
      half8 qv8 = ((const half8*)(qh + (size_t)s * DIM))[l32];
      float p = 0.f;
#pragma unroll
      for (int i = 0; i < 8; ++i) p += (float)qv8[i] * kf[i];
      p += __shfl_xor(p, 1);
      p += __shfl_xor(p, 2);  // head score at all 4 lanes of the head
      p *= scale;
      // softmax over 8 heads (within the 32-lane group):
      // butterfly over lane bits 2,3,4 visits each head exactly once at fixed
      // (bit0,bit1) -> ssum == sum over heads (NOT 4x; that was the R1 bug).
      float m = p;
      m = fmaxf(m, __shfl_xor(m, 4));
      m = fmaxf(m, __shfl_xor(m, 8));
      m = fmaxf(m, __shfl_xor(m, 16));
      float ex = __expf(p - m);
      float ssum = ex;
      ssum += __shfl_xor(ssum, 4);
      ssum += __shfl_xor(ssum, 8);
      ssum += __shfl_xor(ssum, 16);
      float a = valid ? (ex / ssum) : 0.f;
      // accumulate v[s] * a
      half8 vv8 = ((const half8*)(vh + (size_t)s * DIM))[l32];
#pragma unroll
      for (int i = 0; i < 8; ++i) acc[i] += (float)vv8[i] * a;
    }
  }

  // combine the two half-wave accumulators
#pragma unroll
  for (int i = 0; i < 8; ++i) acc[i] += __shfl_xor(acc[i], 32);
  if (hi == 0) {
    half8 o;
#pragma unroll
    for (int i = 0; i < 8; ++i) o[i] = (_Float16)acc[i];
    ((half8*)(hh + (size_t)n * DIM))[l32] = o;
  }
}

// ---------------- launch ----------------
extern "C" void kernel_launch(void* const* d_in, const int* in_sizes, int n_in,
                              void* d_out, int out_size, void* d_ws, size_t ws_size,
                              hipStream_t stream) {
  const float* x = (const float*)d_in[0];
  const int* src = (const int*)d_in[1];
  const int* dst = (const int*)d_in[2];
  const float* Wq = (const float*)d_in[3];
  const float* bq = (const float*)d_in[4];
  const float* Wk = (const float*)d_in[5];
  const float* bk = (const float*)d_in[6];
  const float* Wv = (const float*)d_in[7];
  const float* bv = (const float*)d_in[8];
  const float* Wo = (const float*)d_in[9];
  const float* bo = (const float*)d_in[10];

  // workspace carve (all 256B-aligned sizes)
  char* p = (char*)d_ws;
  const size_t SZ_NODE_H = (size_t)N_NODES * DIM * sizeof(_Float16);  // 5,120,000
  const size_t SZ_W_H = (size_t)DIM * DIM * sizeof(_Float16);         // 131,072
  _Float16* xh = (_Float16*)p; p += SZ_NODE_H;
  _Float16* qh = (_Float16*)p; p += SZ_NODE_H;
  _Float16* kh = (_Float16*)p; p += SZ_NODE_H;
  _Float16* vh = (_Float16*)p; p += SZ_NODE_H;
  _Float16* hh = (_Float16*)p; p += SZ_NODE_H;
  _Float16* Wqh = (_Float16*)p; p += SZ_W_H;
  _Float16* Wkh = (_Float16*)p; p += SZ_W_H;
  _Float16* Wvh = (_Float16*)p; p += SZ_W_H;
  _Float16* Woh = (_Float16*)p; p += SZ_W_H;
  int* counts = (int*)p; p += 40192;   // 10000 ints, padded
  int* offs = (int*)p; p += 40192;     // 10001 ints, padded
  int* cursor = (int*)p; p += 40192;   // 10000 ints, padded
  int* elist = (int*)p; p += (size_t)N_EDGES * sizeof(int);

  hipMemsetAsync(counts, 0, N_NODES * sizeof(int), stream);

  // fp32 -> fp16
  cvt_f2h<<<(N_NODES * DIM / 8 + 255) / 256, 256, 0, stream>>>(x, xh, N_NODES * DIM / 8);
  cvt4_f2h<<<dim3(32, 4), 256, 0, stream>>>(Wq, Wk, Wv, Wo, Wqh, Wkh, Wvh, Woh);

  // QKV projections
  gemm_qkv<<<dim3(157, 4, 3), 256, 0, stream>>>(xh, Wqh, Wkh, Wvh, bq, bk, bv,
                                                qh, kh, vh, N_NODES);

  // CSR by destination
  count_k<<<(N_EDGES + 255) / 256, 256, 0, stream>>>(dst, counts);
  scan_k<<<1, 256, 0, stream>>>(counts, offs, cursor);
  scatter_k<<<(N_EDGES + 255) / 256, 256, 0, stream>>>(dst, cursor, elist);

  // fused attention aggregate -> hh (fp16)
  aggregate_k<<<(N_NODES + 3) / 4, 256, 0, stream>>>(qh, kh, vh, src, elist, offs, hh);

  // output projection (fp32 out)
  gemm_out<<<dim3(157, 4, 1), 256, 0, stream>>>(hh, Woh, bo, (float*)d_out, N_NODES);
}

// Round 3
// 251.153 us; speedup vs baseline: 1.0593x; 1.0593x over previous
//
#include <hip/hip_runtime.h>

#define N_NODES 10000
#define N_EDGES 320000
#define DIM 256

typedef _Float16 half8 __attribute__((ext_vector_type(8)));
typedef _Float16 half2v __attribute__((ext_vector_type(2)));
typedef float floatx4 __attribute__((ext_vector_type(4)));

#define QK_SCALE 0.17677669529663687f  // 1/sqrt(32), folded into q at GEMM epilogue

// ---------------- fp32 -> fp16 conversion ----------------
__device__ __forceinline__ half8 cvt8(const float4 a, const float4 b) {
  half8 o;
  o[0] = (_Float16)a.x; o[1] = (_Float16)a.y; o[2] = (_Float16)a.z; o[3] = (_Float16)a.w;
  o[4] = (_Float16)b.x; o[5] = (_Float16)b.y; o[6] = (_Float16)b.z; o[7] = (_Float16)b.w;
  return o;
}

__global__ void cvt_f2h(const float* __restrict__ in, _Float16* __restrict__ out, int n8) {
  int i = blockIdx.x * blockDim.x + threadIdx.x;
  if (i >= n8) return;
  const float4* p = (const float4*)in;
  ((half8*)out)[i] = cvt8(p[2 * i], p[2 * i + 1]);
}

__global__ void cvt4_f2h(const float* __restrict__ a0, const float* __restrict__ a1,
                         const float* __restrict__ a2, const float* __restrict__ a3,
                         _Float16* __restrict__ o0, _Float16* __restrict__ o1,
                         _Float16* __restrict__ o2, _Float16* __restrict__ o3) {
  int w = blockIdx.y;
  const float* in = (w == 0) ? a0 : (w == 1) ? a1 : (w == 2) ? a2 : a3;
  _Float16* out = (w == 0) ? o0 : (w == 1) ? o1 : (w == 2) ? o2 : o3;
  int i = blockIdx.x * blockDim.x + threadIdx.x;  // 0..8191
  const float4* p = (const float4*)in;
  ((half8*)out)[i] = cvt8(p[2 * i], p[2 * i + 1]);
}

// ---------------- fp16 MFMA GEMM: Y[M,:] = (X[M,256] @ W[256,256]^T + b) * sc ----------------
// Wave computes a 16x64 tile. A-frag: lane holds X[m0+(lane&15)][k0+quad*8+j].
// B-frag: lane holds W[n0+t*16+(lane&15)][k0+quad*8+j]. C/D: col=lane&15, row=quad*4+reg.
// Y has row stride ldY with column offset offY (for q|v interleaved rows).
template <typename OutT>
__device__ __forceinline__ void gemm_body(const _Float16* __restrict__ X,
                                          const _Float16* __restrict__ W,
                                          const float* __restrict__ bias,
                                          OutT* __restrict__ Y, int M, int ldY,
                                          int offY, float sc) {
  int wid = threadIdx.x >> 6;
  int lane = threadIdx.x & 63;
  int quad = lane >> 4;
  int l16 = lane & 15;
  int m0 = blockIdx.x * 64 + wid * 16;
  int n0 = blockIdx.y * 64;
  int row = m0 + l16;
  int rowc = (row < M) ? row : (M - 1);
  const half8* Xr = (const half8*)(X + (size_t)rowc * DIM);

  floatx4 acc[4];
#pragma unroll
  for (int t = 0; t < 4; ++t) acc[t] = (floatx4){0.f, 0.f, 0.f, 0.f};

#pragma unroll
  for (int kk = 0; kk < 8; ++kk) {
    half8 a = Xr[kk * 4 + quad];
#pragma unroll
    for (int t = 0; t < 4; ++t) {
      const half8* Wr = (const half8*)(W + (size_t)(n0 + t * 16 + l16) * DIM);
      half8 b = Wr[kk * 4 + quad];
      acc[t] = __builtin_amdgcn_mfma_f32_16x16x32_f16(a, b, acc[t], 0, 0, 0);
    }
  }

#pragma unroll
  for (int t = 0; t < 4; ++t) {
    int col = n0 + t * 16 + l16;
    float bv = bias[col];
#pragma unroll
    for (int r = 0; r < 4; ++r) {
      int rr = m0 + quad * 4 + r;
      if (rr < M) {
        float val = (acc[t][r] + bv) * sc;
        Y[(size_t)rr * ldY + offY + col] = (OutT)val;
      }
    }
  }
}

__global__ void __launch_bounds__(256) gemm_qkv(
    const _Float16* __restrict__ xh,
    const _Float16* __restrict__ Wq, const _Float16* __restrict__ Wk,
    const _Float16* __restrict__ Wv,
    const float* __restrict__ bq, const float* __restrict__ bk,
    const float* __restrict__ bv,
    _Float16* __restrict__ qv, _Float16* __restrict__ kh, int M) {
  int z = blockIdx.z;
  const _Float16* W = (z == 0) ? Wq : (z == 1) ? Wk : Wv;
  const float* b = (z == 0) ? bq : (z == 1) ? bk : bv;
  _Float16* Y = (z == 1) ? kh : qv;
  int ld = (z == 1) ? 256 : 512;
  int off = (z == 2) ? 256 : 0;
  float sc = (z == 0) ? QK_SCALE : 1.0f;
  gemm_body<_Float16>(xh, W, b, Y, M, ld, off, sc);
}

__global__ void __launch_bounds__(256) gemm_out(
    const _Float16* __restrict__ hh, const _Float16* __restrict__ Wo,
    const float* __restrict__ bo, float* __restrict__ out, int M) {
  gemm_body<float>(hh, Wo, bo, out, M, 256, 0, 1.0f);
}

// ---------------- CSR build ----------------
__global__ void count_k(const int* __restrict__ dst, int* __restrict__ counts) {
  int e = blockIdx.x * blockDim.x + threadIdx.x;
  if (e < N_EDGES) atomicAdd(&counts[dst[e]], 1);
}

__global__ void scan_k(const int* __restrict__ counts, int* __restrict__ offs,
                       int* __restrict__ cursor) {
  __shared__ int ssum[256];
  int t = threadIdx.x;
  const int CH = 40;  // 256*40 = 10240 >= 10000
  int begin = t * CH;
  int end = begin + CH;
  if (end > N_NODES) end = N_NODES;
  int s = 0;
  for (int i = begin; i < end; ++i) s += counts[i];
  ssum[t] = s;
  __syncthreads();
  if (t == 0) {
    int run = 0;
    for (int i = 0; i < 256; ++i) {
      int c = ssum[i];
      ssum[i] = run;
      run += c;
    }
    offs[N_NODES] = run;  // == N_EDGES
  }
  __syncthreads();
  int run = ssum[t];
  for (int i = begin; i < end; ++i) {
    offs[i] = run;
    cursor[i] = run;
    run += counts[i];
  }
}

// stores src[e] (not e) so the aggregate needs no second indirection
__global__ void scatter_k(const int* __restrict__ dst, const int* __restrict__ src,
                          int* __restrict__ cursor, int* __restrict__ slist) {
  int e = blockIdx.x * blockDim.x + threadIdx.x;
  if (e < N_EDGES) {
    int pos = atomicAdd(&cursor[dst[e]], 1);
    slist[pos] = src[e];
  }
}

// ---------------- fused score+softmax+aggregate ----------------
// One wave per node; 16 lanes per edge -> 4 edges per wave-iteration.
// Lane (g=lane>>4, l16=lane&15) holds dims j*128 + l16*8 .. +7 for j=0,1 of
// edge (iter*4+g). Head of (j,l16) = 4j + (l16>>2) -> each lane covers 2 heads.
// Dot reduce over lane bits 0,1; head softmax over lane bits 2,3 (+local j pair).
// q is pre-scaled by 1/sqrt(32); qv rows are [q(256)|v(256)] contiguous 1KB.
__global__ void __launch_bounds__(128) aggregate_k(
    const _Float16* __restrict__ qv, const _Float16* __restrict__ kh,
    const int* __restrict__ slist, const int* __restrict__ offs,
    _Float16* __restrict__ hh) {
  int lane = threadIdx.x & 63;
  int n = blockIdx.x * 2 + (threadIdx.x >> 6);
  if (n >= N_NODES) return;
  int l16 = lane & 15;
  int g = lane >> 4;

  const half8* krow = (const half8*)(kh + (size_t)n * DIM);
  half8 k0 = krow[l16];       // dims l16*8..
  half8 k1 = krow[16 + l16];  // dims 128 + l16*8..

  float acc0[8], acc1[8];
#pragma unroll
  for (int i = 0; i < 8; ++i) { acc0[i] = 0.f; acc1[i] = 0.f; }

  int e0 = offs[n];
  int deg = offs[n + 1] - e0;

  for (int base = 0; base < deg; base += 64) {
    int nb = deg - base;
    if (nb > 64) nb = 64;
    int sid = 0;
    if (lane < nb) sid = slist[e0 + base + lane];
    int iters = (nb + 3) >> 2;

    // prefetch iteration 0
    int idx = g;
    int s = __shfl(sid, idx);
    const half8* r = (const half8*)(qv + (size_t)s * 512);
    half8 q0 = r[l16], q1 = r[16 + l16], v0 = r[32 + l16], v1 = r[48 + l16];
    bool valid = idx < nb;

    for (int jj = 0; jj < iters; ++jj) {
      half8 nq0, nq1, nv0, nv1;
      bool nvalid = false;
      if (jj + 1 < iters) {
        int nidx = (jj + 1) * 4 + g;
        int ns = __shfl(sid, nidx);
        const half8* nr = (const half8*)(qv + (size_t)ns * 512);
        nq0 = nr[l16]; nq1 = nr[16 + l16]; nv0 = nr[32 + l16]; nv1 = nr[48 + l16];
        nvalid = nidx < nb;
      }
      // dot partials via v_dot2_f32_f16
      float p0 = 0.f, p1 = 0.f;
#pragma unroll
      for (int i = 0; i < 4; ++i) {
        half2v qa = __builtin_shufflevector(q0, q0, 0, 1);
        half2v ka = __builtin_shufflevector(k0, k0, 0, 1);
        (void)qa; (void)ka;
      }
#pragma unroll
      for (int i = 0; i < 8; ++i) {
        p0 += (float)q0[i] * (float)k0[i];
        p1 += (float)q1[i] * (float)k1[i];
      }
      p0 += __shfl_xor(p0, 1);
      p0 += __shfl_xor(p0, 2);
      p1 += __shfl_xor(p1, 1);
      p1 += __shfl_xor(p1, 2);
      // softmax over 8 heads: local pair (p0: head a, p1: head a+4), then bits 2,3
      float m = fmaxf(p0, p1);
      m = fmaxf(m, __shfl_xor(m, 4));
      m = fmaxf(m, __shfl_xor(m, 8));
      float ex0 = __expf(p0 - m);
      float ex1 = __expf(p1 - m);
      float ssum = ex0 + ex1;
      ssum += __shfl_xor(ssum, 4);
      ssum += __shfl_xor(ssum, 8);
      float inv = __frcp_rn(ssum);
      float a0 = valid ? ex0 * inv : 0.f;
      float a1 = valid ? ex1 * inv : 0.f;
#pragma unroll
      for (int i = 0; i < 8; ++i) {
        acc0[i] += (float)v0[i] * a0;
        acc1[i] += (float)v1[i] * a1;
      }
      q0 = nq0; q1 = nq1; v0 = nv0; v1 = nv1;
      valid = nvalid;
    }
  }

  // reduce the 4 edge-groups (all hold identical dim mapping)
#pragma unroll
  for (int i = 0; i < 8; ++i) {
    acc0[i] += __shfl_xor(acc0[i], 16);
    acc0[i] += __shfl_xor(acc0[i], 32);
    acc1[i] += __shfl_xor(acc1[i], 16);
    acc1[i] += __shfl_xor(acc1[i], 32);
  }
  if (g == 0) {
    half8 o0, o1;
#pragma unroll
    for (int i = 0; i < 8; ++i) { o0[i] = (_Float16)acc0[i]; o1[i] = (_Float16)acc1[i]; }
    half8* hrow = (half8*)(hh + (size_t)n * DIM);
    hrow[l16] = o0;
    hrow[16 + l16] = o1;
  }
}

// ---------------- launch ----------------
extern "C" void kernel_launch(void* const* d_in, const int* in_sizes, int n_in,
                              void* d_out, int out_size, void* d_ws, size_t ws_size,
                              hipStream_t stream) {
  const float* x = (const float*)d_in[0];
  const int* src = (const int*)d_in[1];
  const int* dst = (const int*)d_in[2];
  const float* Wq = (const float*)d_in[3];
  const float* bq = (const float*)d_in[4];
  const float* Wk = (const float*)d_in[5];
  const float* bk = (const float*)d_in[6];
  const float* Wv = (const float*)d_in[7];
  const float* bv = (const float*)d_in[8];
  const float* Wo = (const float*)d_in[9];
  const float* bo = (const float*)d_in[10];

  char* p = (char*)d_ws;
  const size_t SZ_NODE_H = (size_t)N_NODES * DIM * sizeof(_Float16);  // 5,120,000
  const size_t SZ_W_H = (size_t)DIM * DIM * sizeof(_Float16);         // 131,072
  _Float16* xh = (_Float16*)p; p += SZ_NODE_H;
  _Float16* qvv = (_Float16*)p; p += 2 * SZ_NODE_H;  // interleaved [q|v] rows, 1KB each
  _Float16* kh = (_Float16*)p; p += SZ_NODE_H;
  _Float16* hh = (_Float16*)p; p += SZ_NODE_H;
  _Float16* Wqh = (_Float16*)p; p += SZ_W_H;
  _Float16* Wkh = (_Float16*)p; p += SZ_W_H;
  _Float16* Wvh = (_Float16*)p; p += SZ_W_H;
  _Float16* Woh = (_Float16*)p; p += SZ_W_H;
  int* counts = (int*)p; p += 40192;
  int* offs = (int*)p; p += 40192;
  int* cursor = (int*)p; p += 40192;
  int* slist = (int*)p; p += (size_t)N_EDGES * sizeof(int);

  hipMemsetAsync(counts, 0, N_NODES * sizeof(int), stream);

  cvt_f2h<<<(N_NODES * DIM / 8 + 255) / 256, 256, 0, stream>>>(x, xh, N_NODES * DIM / 8);
  cvt4_f2h<<<dim3(32, 4), 256, 0, stream>>>(Wq, Wk, Wv, Wo, Wqh, Wkh, Wvh, Woh);

  gemm_qkv<<<dim3(157, 4, 3), 256, 0, stream>>>(xh, Wqh, Wkh, Wvh, bq, bk, bv,
                                                qvv, kh, N_NODES);

  count_k<<<(N_EDGES + 255) / 256, 256, 0, stream>>>(dst, counts);
  scan_k<<<1, 256, 0, stream>>>(counts, offs, cursor);
  scatter_k<<<(N_EDGES + 255) / 256, 256, 0, stream>>>(dst, src, cursor, slist);

  aggregate_k<<<(N_NODES + 1) / 2, 128, 0, stream>>>(qvv, kh, slist, offs, hh);

  gemm_out<<<dim3(157, 4, 1), 256, 0, stream>>>(hh, Woh, bo, (float*)d_out, N_NODES);
}

// Round 4
// 228.828 us; speedup vs baseline: 1.1626x; 1.0976x over previous
//
#include <hip/hip_runtime.h>

#define N_NODES 10000
#define N_EDGES 320000
#define DIM 256

typedef _Float16 half8 __attribute__((ext_vector_type(8)));
typedef float floatx4 __attribute__((ext_vector_type(4)));

#define QK_SCALE 0.17677669529663687f  // 1/sqrt(32), folded into Wq/bq

// ---------------- fp32 -> fp16 conversion ----------------
__device__ __forceinline__ half8 cvt8s(const float4 a, const float4 b, float sc) {
  half8 o;
  o[0] = (_Float16)(a.x * sc); o[1] = (_Float16)(a.y * sc);
  o[2] = (_Float16)(a.z * sc); o[3] = (_Float16)(a.w * sc);
  o[4] = (_Float16)(b.x * sc); o[5] = (_Float16)(b.y * sc);
  o[6] = (_Float16)(b.z * sc); o[7] = (_Float16)(b.w * sc);
  return o;
}

__global__ void cvt_f2h(const float* __restrict__ in, _Float16* __restrict__ out, int n8) {
  int i = blockIdx.x * blockDim.x + threadIdx.x;
  if (i >= n8) return;
  const float4* p = (const float4*)in;
  ((half8*)out)[i] = cvt8s(p[2 * i], p[2 * i + 1], 1.0f);
}

// W_cat rows: [0,256) = Wq * QK_SCALE, [256,512) = Wv, [512,768) = Wk; Wo separate.
__global__ void cvt_w(const float* __restrict__ Wq, const float* __restrict__ Wk,
                      const float* __restrict__ Wv, const float* __restrict__ Wo,
                      _Float16* __restrict__ Wcat, _Float16* __restrict__ Woh) {
  int w = blockIdx.y;
  const float* in = (w == 0) ? Wq : (w == 1) ? Wv : (w == 2) ? Wk : Wo;
  _Float16* out = (w < 3) ? (Wcat + (size_t)w * 65536) : Woh;
  float sc = (w == 0) ? QK_SCALE : 1.0f;
  int i = blockIdx.x * blockDim.x + threadIdx.x;  // 0..8191 half8s
  const float4* p = (const float4*)in;
  ((half8*)out)[i] = cvt8s(p[2 * i], p[2 * i + 1], sc);
}

__global__ void bias_cat(const float* __restrict__ bq, const float* __restrict__ bk,
                         const float* __restrict__ bv, float* __restrict__ bc) {
  int t = threadIdx.x;  // 256 threads
  bc[t] = bq[t] * QK_SCALE;
  bc[256 + t] = bv[t];
  bc[512 + t] = bk[t];
}

// ---------------- tiled fp16 MFMA GEMM: Y[M,N] = X[M,256] @ B[N,256]^T + bias ----------------
// BM=BN=128, BK=64 (4 k-steps), 256 threads = 4 waves, each wave 64x64 (4x4 MFMA frags).
// LDS row stride 72 halves (=144B): bank base rotates 4/row -> <=2-way conflicts (free).
// MODE 0: dual fp16 dest (col<512 -> qv ld512; col>=512 -> kh ld256). MODE 1: fp32 out ld256.
template <int MODE>
__global__ void __launch_bounds__(256) gemm_tiled(
    const _Float16* __restrict__ A, const _Float16* __restrict__ B,
    const float* __restrict__ bias,
    _Float16* __restrict__ qv, _Float16* __restrict__ kh,
    float* __restrict__ outf, int M) {
  __shared__ _Float16 As[128 * 72];
  __shared__ _Float16 Bs[128 * 72];
  int t = threadIdx.x;
  int lane = t & 63;
  int wid = t >> 6;
  int l16 = lane & 15;
  int quad = lane >> 4;
  int wm = wid >> 1, wn = wid & 1;
  int m0 = blockIdx.x * 128;
  int n0 = blockIdx.y * 128;

  floatx4 acc[4][4];
#pragma unroll
  for (int i = 0; i < 4; ++i)
#pragma unroll
    for (int j = 0; j < 4; ++j) acc[i][j] = (floatx4){0.f, 0.f, 0.f, 0.f};

  const half8* Ag = (const half8*)A;
  const half8* Bg = (const half8*)B;
  half8* As8 = (half8*)As;
  half8* Bs8 = (half8*)Bs;

  // precompute staging indices (4 sweeps of 256 threads over 1024 half8 chunks)
  int srow = t >> 3;      // 0..31, +32 per sweep
  int skc = t & 7;        // k-chunk within row

  for (int ks = 0; ks < 4; ++ks) {
    __syncthreads();
#pragma unroll
    for (int sweep = 0; sweep < 4; ++sweep) {
      int row = sweep * 32 + srow;
      int arow = m0 + row;
      if (arow >= M) arow = M - 1;
      As8[row * 9 + skc] = Ag[(size_t)arow * 32 + ks * 8 + skc];
      Bs8[row * 9 + skc] = Bg[(size_t)(n0 + row) * 32 + ks * 8 + skc];
    }
    __syncthreads();
#pragma unroll
    for (int kk = 0; kk < 2; ++kk) {
      half8 af[4], bf[4];
#pragma unroll
      for (int i = 0; i < 4; ++i) {
        af[i] = As8[(wm * 64 + i * 16 + l16) * 9 + kk * 4 + quad];
        bf[i] = Bs8[(wn * 64 + i * 16 + l16) * 9 + kk * 4 + quad];
      }
#pragma unroll
      for (int mi = 0; mi < 4; ++mi)
#pragma unroll
        for (int ni = 0; ni < 4; ++ni)
          acc[mi][ni] =
              __builtin_amdgcn_mfma_f32_16x16x32_f16(af[mi], bf[ni], acc[mi][ni], 0, 0, 0);
    }
  }

#pragma unroll
  for (int mi = 0; mi < 4; ++mi) {
#pragma unroll
    for (int ni = 0; ni < 4; ++ni) {
      int col = n0 + wn * 64 + ni * 16 + l16;
      float bv = bias[col];
#pragma unroll
      for (int r = 0; r < 4; ++r) {
        int row = m0 + wm * 64 + mi * 16 + quad * 4 + r;
        if (row < M) {
          float val = acc[mi][ni][r] + bv;
          if (MODE == 0) {
            if (col < 512)
              qv[(size_t)row * 512 + col] = (_Float16)val;
            else
              kh[(size_t)row * 256 + (col - 512)] = (_Float16)val;
          } else {
            outf[(size_t)row * 256 + col] = val;
          }
        }
      }
    }
  }
}

// ---------------- CSR build ----------------
__global__ void count_k(const int* __restrict__ dst, int* __restrict__ counts) {
  int e = blockIdx.x * blockDim.x + threadIdx.x;
  if (e < N_EDGES) atomicAdd(&counts[dst[e]], 1);
}

__global__ void scan_k(const int* __restrict__ counts, int* __restrict__ offs,
                       int* __restrict__ cursor) {
  __shared__ int ssum[256];
  int t = threadIdx.x;
  const int CH = 40;  // 256*40 = 10240 >= 10000
  int begin = t * CH;
  int end = begin + CH;
  if (end > N_NODES) end = N_NODES;
  int s = 0;
  for (int i = begin; i < end; ++i) s += counts[i];
  ssum[t] = s;
  __syncthreads();
  if (t == 0) {
    int run = 0;
    for (int i = 0; i < 256; ++i) {
      int c = ssum[i];
      ssum[i] = run;
      run += c;
    }
    offs[N_NODES] = run;  // == N_EDGES
  }
  __syncthreads();
  int run = ssum[t];
  for (int i = begin; i < end; ++i) {
    offs[i] = run;
    cursor[i] = run;
    run += counts[i];
  }
}

// stores src[e] (not e) so the aggregate needs no second indirection
__global__ void scatter_k(const int* __restrict__ dst, const int* __restrict__ src,
                          int* __restrict__ cursor, int* __restrict__ slist) {
  int e = blockIdx.x * blockDim.x + threadIdx.x;
  if (e < N_EDGES) {
    int pos = atomicAdd(&cursor[dst[e]], 1);
    slist[pos] = src[e];
  }
}

// ---------------- fused score+softmax+aggregate ----------------
// One wave per node; 16 lanes per edge -> 4 edges per wave-iteration.
// Lane (g=lane>>4, l16=lane&15) holds dims j*128 + l16*8 .. +7 for j=0,1 of
// edge (iter*4+g). Head of (j,l16) = 4j + (l16>>2). Dot reduce over lane bits
// 0,1; head softmax over bits 2,3 + local j pair. q pre-scaled by 1/sqrt(32);
// qv rows are [q(256)|v(256)] contiguous 1KB.
__global__ void __launch_bounds__(128) aggregate_k(
    const _Float16* __restrict__ qv, const _Float16* __restrict__ kh,
    const int* __restrict__ slist, const int* __restrict__ offs,
    _Float16* __restrict__ hh) {
  int lane = threadIdx.x & 63;
  int n = blockIdx.x * 2 + (threadIdx.x >> 6);
  if (n >= N_NODES) return;
  int l16 = lane & 15;
  int g = lane >> 4;

  const half8* krow = (const half8*)(kh + (size_t)n * DIM);
  half8 k0 = krow[l16];
  half8 k1 = krow[16 + l16];

  float acc0[8], acc1[8];
#pragma unroll
  for (int i = 0; i < 8; ++i) { acc0[i] = 0.f; acc1[i] = 0.f; }

  int e0 = offs[n];
  int deg = offs[n + 1] - e0;

  for (int base = 0; base < deg; base += 64) {
    int nb = deg - base;
    if (nb > 64) nb = 64;
    int sid = 0;
    if (lane < nb) sid = slist[e0 + base + lane];
    int iters = (nb + 3) >> 2;

    int idx = g;
    int s = __shfl(sid, idx);
    const half8* r = (const half8*)(qv + (size_t)s * 512);
    half8 q0 = r[l16], q1 = r[16 + l16], v0 = r[32 + l16], v1 = r[48 + l16];
    bool valid = idx < nb;

    for (int jj = 0; jj < iters; ++jj) {
      half8 nq0, nq1, nv0, nv1;
      bool nvalid = false;
      if (jj + 1 < iters) {
        int nidx = (jj + 1) * 4 + g;
        int ns = __shfl(sid, nidx);
        const half8* nr = (const half8*)(qv + (size_t)ns * 512);
        nq0 = nr[l16]; nq1 = nr[16 + l16]; nv0 = nr[32 + l16]; nv1 = nr[48 + l16];
        nvalid = nidx < nb;
      }
      float p0 = 0.f, p1 = 0.f;
#pragma unroll
      for (int i = 0; i < 8; ++i) {
        p0 += (float)q0[i] * (float)k0[i];
        p1 += (float)q1[i] * (float)k1[i];
      }
      p0 += __shfl_xor(p0, 1);
      p0 += __shfl_xor(p0, 2);
      p1 += __shfl_xor(p1, 1);
      p1 += __shfl_xor(p1, 2);
      float m = fmaxf(p0, p1);
      m = fmaxf(m, __shfl_xor(m, 4));
      m = fmaxf(m, __shfl_xor(m, 8));
      float ex0 = __expf(p0 - m);
      float ex1 = __expf(p1 - m);
      float ssum = ex0 + ex1;
      ssum += __shfl_xor(ssum, 4);
      ssum += __shfl_xor(ssum, 8);
      float inv = __frcp_rn(ssum);
      float a0 = valid ? ex0 * inv : 0.f;
      float a1 = valid ? ex1 * inv : 0.f;
#pragma unroll
      for (int i = 0; i < 8; ++i) {
        acc0[i] += (float)v0[i] * a0;
        acc1[i] += (float)v1[i] * a1;
      }
      q0 = nq0; q1 = nq1; v0 = nv0; v1 = nv1;
      valid = nvalid;
    }
  }

#pragma unroll
  for (int i = 0; i < 8; ++i) {
    acc0[i] += __shfl_xor(acc0[i], 16);
    acc0[i] += __shfl_xor(acc0[i], 32);
    acc1[i] += __shfl_xor(acc1[i], 16);
    acc1[i] += __shfl_xor(acc1[i], 32);
  }
  if (g == 0) {
    half8 o0, o1;
#pragma unroll
    for (int i = 0; i < 8; ++i) { o0[i] = (_Float16)acc0[i]; o1[i] = (_Float16)acc1[i]; }
    half8* hrow = (half8*)(hh + (size_t)n * DIM);
    hrow[l16] = o0;
    hrow[16 + l16] = o1;
  }
}

// ---------------- launch ----------------
extern "C" void kernel_launch(void* const* d_in, const int* in_sizes, int n_in,
                              void* d_out, int out_size, void* d_ws, size_t ws_size,
                              hipStream_t stream) {
  const float* x = (const float*)d_in[0];
  const int* src = (const int*)d_in[1];
  const int* dst = (const int*)d_in[2];
  const float* Wq = (const float*)d_in[3];
  const float* bq = (const float*)d_in[4];
  const float* Wk = (const float*)d_in[5];
  const float* bk = (const float*)d_in[6];
  const float* Wv = (const float*)d_in[7];
  const float* bv = (const float*)d_in[8];
  const float* Wo = (const float*)d_in[9];
  const float* bo = (const float*)d_in[10];

  char* p = (char*)d_ws;
  const size_t SZ_NODE_H = (size_t)N_NODES * DIM * sizeof(_Float16);  // 5,120,000
  _Float16* xh = (_Float16*)p; p += SZ_NODE_H;
  _Float16* qvv = (_Float16*)p; p += 2 * SZ_NODE_H;  // [q|v] rows, 1KB each
  _Float16* kh = (_Float16*)p; p += SZ_NODE_H;
  _Float16* hh = (_Float16*)p; p += SZ_NODE_H;
  _Float16* Wcat = (_Float16*)p; p += (size_t)768 * 256 * sizeof(_Float16);
  _Float16* Woh = (_Float16*)p; p += (size_t)256 * 256 * sizeof(_Float16);
  float* bcat = (float*)p; p += 768 * sizeof(float) + 256;
  int* counts = (int*)p; p += 40192;
  int* offs = (int*)p; p += 40192;
  int* cursor = (int*)p; p += 40192;
  int* slist = (int*)p; p += (size_t)N_EDGES * sizeof(int);

  hipMemsetAsync(counts, 0, N_NODES * sizeof(int), stream);

  cvt_f2h<<<(N_NODES * DIM / 8 + 255) / 256, 256, 0, stream>>>(x, xh, N_NODES * DIM / 8);
  cvt_w<<<dim3(32, 4), 256, 0, stream>>>(Wq, Wk, Wv, Wo, Wcat, Woh);
  bias_cat<<<1, 256, 0, stream>>>(bq, bk, bv, bcat);

  // fused QKV projection: [10000,256] @ [768,256]^T
  gemm_tiled<0><<<dim3(79, 6), 256, 0, stream>>>(xh, Wcat, bcat, qvv, kh, nullptr,
                                                 N_NODES);

  count_k<<<(N_EDGES + 255) / 256, 256, 0, stream>>>(dst, counts);
  scan_k<<<1, 256, 0, stream>>>(counts, offs, cursor);
  scatter_k<<<(N_EDGES + 255) / 256, 256, 0, stream>>>(dst, src, cursor, slist);

  aggregate_k<<<(N_NODES + 1) / 2, 128, 0, stream>>>(qvv, kh, slist, offs, hh);

  // output projection: [10000,256] @ [256,256]^T -> fp32
  gemm_tiled<1><<<dim3(79, 2), 256, 0, stream>>>(hh, Woh, bo, nullptr, nullptr,
                                                 (float*)d_out, N_NODES);
}

// Round 5
// 222.422 us; speedup vs baseline: 1.1961x; 1.0288x over previous
//
#include <hip/hip_runtime.h>
#include <stdint.h>

#define N_NODES 10000
#define N_EDGES 320000
#define DIM 256

typedef _Float16 half8 __attribute__((ext_vector_type(8)));
typedef float floatx4 __attribute__((ext_vector_type(4)));

#define QK_SCALE 0.17677669529663687f  // 1/sqrt(32), folded into Wq/bq

// ---------------- async global->LDS (16B per lane, wave-uniform LDS base) ----------------
typedef __attribute__((address_space(3))) uint32_t lds_u32;
typedef __attribute__((address_space(1))) const uint32_t glob_u32;
__device__ __forceinline__ void load16_lds(const _Float16* g, _Float16* l) {
  __builtin_amdgcn_global_load_lds((glob_u32*)g, (lds_u32*)l, 16, 0, 0);
}

// ---------------- fp32 -> fp16 ----------------
__device__ __forceinline__ half8 cvt8s(const float4 a, const float4 b, float sc) {
  half8 o;
  o[0] = (_Float16)(a.x * sc); o[1] = (_Float16)(a.y * sc);
  o[2] = (_Float16)(a.z * sc); o[3] = (_Float16)(a.w * sc);
  o[4] = (_Float16)(b.x * sc); o[5] = (_Float16)(b.y * sc);
  o[6] = (_Float16)(b.z * sc); o[7] = (_Float16)(b.w * sc);
  return o;
}

// ---------------- fused prep: x cvt | weight cvt (+q scale) | edge count ----------------
// blocks [0,1250): x (320000 half8). [1250,1378): weights (4 x 8192 half8).
// [1378,2628): count edges.
__global__ void __launch_bounds__(256) prep_k(
    const float* __restrict__ x, const float* __restrict__ Wq,
    const float* __restrict__ Wk, const float* __restrict__ Wv,
    const float* __restrict__ Wo, const int* __restrict__ dst,
    _Float16* __restrict__ xh, _Float16* __restrict__ Wcat,
    _Float16* __restrict__ Woh, int* __restrict__ counts) {
  int b = blockIdx.x;
  int t = threadIdx.x;
  if (b < 1250) {
    int i = b * 256 + t;  // 320000 = 1250*256 exactly
    const float4* p = (const float4*)x;
    ((half8*)xh)[i] = cvt8s(p[2 * i], p[2 * i + 1], 1.0f);
  } else if (b < 1378) {
    int bb = b - 1250;
    int w = bb >> 5;                 // 0..3
    int i = (bb & 31) * 256 + t;     // 0..8191
    const float* in = (w == 0) ? Wq : (w == 1) ? Wv : (w == 2) ? Wk : Wo;
    _Float16* out = (w < 3) ? (Wcat + (size_t)w * 65536) : Woh;
    float sc = (w == 0) ? QK_SCALE : 1.0f;
    const float4* p = (const float4*)in;
    ((half8*)out)[i] = cvt8s(p[2 * i], p[2 * i + 1], sc);
  } else {
    int e = (b - 1378) * 256 + t;
    if (e < N_EDGES) atomicAdd(&counts[dst[e]], 1);
  }
}

// ---------------- DMA-staged fp16 MFMA GEMM: Y[M,N] = X[M,256] @ B[N,256]^T + bias --------
// BM=BN=128, BK=64, 256 threads = 4 waves, each wave 64x64 (4x4 MFMA frags).
// LDS tile K-major: [8 chunks][128 rows][8 halves]; DMA writes 64 rows of one chunk
// per call (wave-uniform base + lane*16B); fragment reads spread banks by row.
// MODE 0: dual fp16 dest (col<512 -> qv ld512; col>=512 -> kh ld256), bias = (bq*s|bv|bk).
// MODE 1: fp32 out ld256, bias = b0.
template <int MODE>
__global__ void __launch_bounds__(256) gemm_tiled(
    const _Float16* __restrict__ A, const _Float16* __restrict__ B,
    const float* __restrict__ b0, const float* __restrict__ b1,
    const float* __restrict__ b2,
    _Float16* __restrict__ qv, _Float16* __restrict__ kh,
    float* __restrict__ outf, int M) {
  __shared__ _Float16 As[8192];
  __shared__ _Float16 Bs[8192];
  int t = threadIdx.x;
  int lane = t & 63;
  int wid = t >> 6;
  int l16 = lane & 15;
  int quad = lane >> 4;
  int wm = wid >> 1, wn = wid & 1;
  int m0 = blockIdx.x * 128;
  int n0 = blockIdx.y * 128;

  floatx4 acc[4][4];
#pragma unroll
  for (int i = 0; i < 4; ++i)
#pragma unroll
    for (int j = 0; j < 4; ++j) acc[i][j] = (floatx4){0.f, 0.f, 0.f, 0.f};

  for (int ks = 0; ks < 4; ++ks) {
    if (ks) __syncthreads();  // protect LDS reuse
#pragma unroll
    for (int i = 0; i < 4; ++i) {
      int idx = i * 4 + wid;   // 0..15: chunk c = idx>>1, row-half h = idx&1
      int c = idx >> 1;
      int h = idx & 1;
      int r = h * 64 + lane;
      int ar = m0 + r;
      if (ar >= M) ar = M - 1;
      load16_lds(A + (size_t)ar * 256 + ks * 64 + c * 8, &As[(c * 128 + h * 64) * 8]);
      load16_lds(B + (size_t)(n0 + r) * 256 + ks * 64 + c * 8, &Bs[(c * 128 + h * 64) * 8]);
    }
    __syncthreads();  // drains vmcnt (DMA) per barrier semantics
#pragma unroll
    for (int kk = 0; kk < 2; ++kk) {
      int j = kk * 4 + quad;
      half8 af[4], bf[4];
#pragma unroll
      for (int i = 0; i < 4; ++i) {
        af[i] = *(const half8*)&As[(j * 128 + wm * 64 + i * 16 + l16) * 8];
        bf[i] = *(const half8*)&Bs[(j * 128 + wn * 64 + i * 16 + l16) * 8];
      }
#pragma unroll
      for (int mi = 0; mi < 4; ++mi)
#pragma unroll
        for (int ni = 0; ni < 4; ++ni)
          acc[mi][ni] =
              __builtin_amdgcn_mfma_f32_16x16x32_f16(af[mi], bf[ni], acc[mi][ni], 0, 0, 0);
    }
  }

#pragma unroll
  for (int mi = 0; mi < 4; ++mi) {
#pragma unroll
    for (int ni = 0; ni < 4; ++ni) {
      int col = n0 + wn * 64 + ni * 16 + l16;
      float bias;
      if (MODE == 0) {
        bias = (col < 256) ? b0[col] * QK_SCALE
                           : (col < 512) ? b1[col - 256] : b2[col - 512];
      } else {
        bias = b0[col];
      }
#pragma unroll
      for (int r = 0; r < 4; ++r) {
        int row = m0 + wm * 64 + mi * 16 + quad * 4 + r;
        if (row < M) {
          float val = acc[mi][ni][r] + bias;
          if (MODE == 0) {
            if (col < 512)
              qv[(size_t)row * 512 + col] = (_Float16)val;
            else
              kh[(size_t)row * 256 + (col - 512)] = (_Float16)val;
          } else {
            outf[(size_t)row * 256 + col] = val;
          }
        }
      }
    }
  }
}

// ---------------- CSR scan + scatter ----------------
__global__ void scan_k(const int* __restrict__ counts, int* __restrict__ offs,
                       int* __restrict__ cursor) {
  __shared__ int ssum[256];
  int t = threadIdx.x;
  const int CH = 40;  // 256*40 = 10240 >= 10000
  int begin = t * CH;
  int end = begin + CH;
  if (end > N_NODES) end = N_NODES;
  int s = 0;
  for (int i = begin; i < end; ++i) s += counts[i];
  ssum[t] = s;
  __syncthreads();
  if (t == 0) {
    int run = 0;
    for (int i = 0; i < 256; ++i) {
      int c = ssum[i];
      ssum[i] = run;
      run += c;
    }
    offs[N_NODES] = run;  // == N_EDGES
  }
  __syncthreads();
  int run = ssum[t];
  for (int i = begin; i < end; ++i) {
    offs[i] = run;
    cursor[i] = run;
    run += counts[i];
  }
}

// stores src[e] so the aggregate needs no second indirection
__global__ void scatter_k(const int* __restrict__ dst, const int* __restrict__ src,
                          int* __restrict__ cursor, int* __restrict__ slist) {
  int e = blockIdx.x * blockDim.x + threadIdx.x;
  if (e < N_EDGES) {
    int pos = atomicAdd(&cursor[dst[e]], 1);
    slist[pos] = src[e];
  }
}

// ---------------- fused score+softmax+aggregate ----------------
// One wave per node; 16 lanes per edge -> 4 edges per wave-iteration.
// Lane (g=lane>>4, l16=lane&15) holds dims j*128 + l16*8 .. +7, j=0,1 of edge
// (iter*4+g). Head of (j,l16) = 4j + (l16>>2). Dot reduce over lane bits 0,1;
// head softmax over bits 2,3 + local j pair. No max-subtraction: |score| <~ 30,
// exp well within fp32 range; softmax ratio unchanged.
// q pre-scaled by 1/sqrt(32); qv rows are [q(256)|v(256)] contiguous 1KB.
__global__ void __launch_bounds__(128) aggregate_k(
    const _Float16* __restrict__ qv, const _Float16* __restrict__ kh,
    const int* __restrict__ slist, const int* __restrict__ offs,
    _Float16* __restrict__ hh) {
  int lane = threadIdx.x & 63;
  int n = blockIdx.x * 2 + (threadIdx.x >> 6);
  if (n >= N_NODES) return;
  int l16 = lane & 15;
  int g = lane >> 4;

  const half8* krow = (const half8*)(kh + (size_t)n * DIM);
  half8 k0 = krow[l16];
  half8 k1 = krow[16 + l16];

  float acc0[8], acc1[8];
#pragma unroll
  for (int i = 0; i < 8; ++i) { acc0[i] = 0.f; acc1[i] = 0.f; }

  int e0 = offs[n];
  int deg = offs[n + 1] - e0;

  for (int base = 0; base < deg; base += 64) {
    int nb = deg - base;
    if (nb > 64) nb = 64;
    int sid = 0;
    if (lane < nb) sid = slist[e0 + base + lane];
    int iters = (nb + 3) >> 2;

    int idx = g;
    int s = __shfl(sid, idx);
    const half8* r = (const half8*)(qv + (size_t)s * 512);
    half8 q0 = r[l16], q1 = r[16 + l16], v0 = r[32 + l16], v1 = r[48 + l16];
    bool valid = idx < nb;

    for (int jj = 0; jj < iters; ++jj) {
      half8 nq0, nq1, nv0, nv1;
      bool nvalid = false;
      if (jj + 1 < iters) {
        int nidx = (jj + 1) * 4 + g;
        int ns = __shfl(sid, nidx);
        const half8* nr = (const half8*)(qv + (size_t)ns * 512);
        nq0 = nr[l16]; nq1 = nr[16 + l16]; nv0 = nr[32 + l16]; nv1 = nr[48 + l16];
        nvalid = nidx < nb;
      }
      float p0 = 0.f, p1 = 0.f;
#pragma unroll
      for (int i = 0; i < 8; ++i) {
        p0 += (float)q0[i] * (float)k0[i];
        p1 += (float)q1[i] * (float)k1[i];
      }
      p0 += __shfl_xor(p0, 1);
      p1 += __shfl_xor(p1, 1);
      p0 += __shfl_xor(p0, 2);
      p1 += __shfl_xor(p1, 2);
      float ex0 = __expf(p0);
      float ex1 = __expf(p1);
      float ssum = ex0 + ex1;
      ssum += __shfl_xor(ssum, 4);
      ssum += __shfl_xor(ssum, 8);
      float inv = __frcp_rn(ssum);
      float a0 = valid ? ex0 * inv : 0.f;
      float a1 = valid ? ex1 * inv : 0.f;
#pragma unroll
      for (int i = 0; i < 8; ++i) {
        acc0[i] += (float)v0[i] * a0;
        acc1[i] += (float)v1[i] * a1;
      }
      q0 = nq0; q1 = nq1; v0 = nv0; v1 = nv1;
      valid = nvalid;
    }
  }

#pragma unroll
  for (int i = 0; i < 8; ++i) {
    acc0[i] += __shfl_xor(acc0[i], 16);
    acc0[i] += __shfl_xor(acc0[i], 32);
    acc1[i] += __shfl_xor(acc1[i], 16);
    acc1[i] += __shfl_xor(acc1[i], 32);
  }
  if (g == 0) {
    half8 o0, o1;
#pragma unroll
    for (int i = 0; i < 8; ++i) { o0[i] = (_Float16)acc0[i]; o1[i] = (_Float16)acc1[i]; }
    half8* hrow = (half8*)(hh + (size_t)n * DIM);
    hrow[l16] = o0;
    hrow[16 + l16] = o1;
  }
}

// ---------------- launch ----------------
extern "C" void kernel_launch(void* const* d_in, const int* in_sizes, int n_in,
                              void* d_out, int out_size, void* d_ws, size_t ws_size,
                              hipStream_t stream) {
  const float* x = (const float*)d_in[0];
  const int* src = (const int*)d_in[1];
  const int* dst = (const int*)d_in[2];
  const float* Wq = (const float*)d_in[3];
  const float* bq = (const float*)d_in[4];
  const float* Wk = (const float*)d_in[5];
  const float* bk = (const float*)d_in[6];
  const float* Wv = (const float*)d_in[7];
  const float* bv = (const float*)d_in[8];
  const float* Wo = (const float*)d_in[9];
  const float* bo = (const float*)d_in[10];

  char* p = (char*)d_ws;
  const size_t SZ_NODE_H = (size_t)N_NODES * DIM * sizeof(_Float16);  // 5,120,000
  _Float16* xh = (_Float16*)p; p += SZ_NODE_H;
  _Float16* qvv = (_Float16*)p; p += 2 * SZ_NODE_H;  // [q|v] rows, 1KB each
  _Float16* kh = (_Float16*)p; p += SZ_NODE_H;
  _Float16* hh = (_Float16*)p; p += SZ_NODE_H;
  _Float16* Wcat = (_Float16*)p; p += (size_t)768 * 256 * sizeof(_Float16);
  _Float16* Woh = (_Float16*)p; p += (size_t)256 * 256 * sizeof(_Float16);
  int* counts = (int*)p; p += 40192;
  int* offs = (int*)p; p += 40192;
  int* cursor = (int*)p; p += 40192;
  int* slist = (int*)p; p += (size_t)N_EDGES * sizeof(int);

  hipMemsetAsync(counts, 0, N_NODES * sizeof(int), stream);

  // fused cvt(x) + cvt(W, q-scale) + edge count
  prep_k<<<2628, 256, 0, stream>>>(x, Wq, Wk, Wv, Wo, dst, xh, Wcat, Woh, counts);

  // fused QKV projection: [10000,256] @ [768,256]^T
  gemm_tiled<0><<<dim3(79, 6), 256, 0, stream>>>(xh, Wcat, bq, bv, bk, qvv, kh,
                                                 nullptr, N_NODES);

  scan_k<<<1, 256, 0, stream>>>(counts, offs, cursor);
  scatter_k<<<(N_EDGES + 255) / 256, 256, 0, stream>>>(dst, src, cursor, slist);

  aggregate_k<<<(N_NODES + 1) / 2, 128, 0, stream>>>(qvv, kh, slist, offs, hh);

  // output projection: [10000,256] @ [256,256]^T -> fp32
  gemm_tiled<1><<<dim3(79, 2), 256, 0, stream>>>(hh, Woh, bo, nullptr, nullptr,
                                                 nullptr, nullptr, (float*)d_out,
                                                 N_NODES);
}

// Round 6
// 220.943 us; speedup vs baseline: 1.2041x; 1.0067x over previous
//
#include <hip/hip_runtime.h>
#include <stdint.h>

#define N_NODES 10000
#define N_EDGES 320000
#define DIM 256

typedef _Float16 half8 __attribute__((ext_vector_type(8)));
typedef _Float16 half2t __attribute__((ext_vector_type(2)));
typedef float floatx4 __attribute__((ext_vector_type(4)));

#define QK_SCALE 0.17677669529663687f  // 1/sqrt(32), folded into Wq/bq

// ---------------- async global->LDS (16B per lane, wave-uniform LDS base) ----------------
typedef __attribute__((address_space(3))) uint32_t lds_u32;
typedef __attribute__((address_space(1))) const uint32_t glob_u32;
__device__ __forceinline__ void load16_lds(const _Float16* g, _Float16* l) {
  __builtin_amdgcn_global_load_lds((glob_u32*)g, (lds_u32*)l, 16, 0, 0);
}

// ---------------- fp32 -> fp16 ----------------
__device__ __forceinline__ half8 cvt8s(const float4 a, const float4 b, float sc) {
  half8 o;
  o[0] = (_Float16)(a.x * sc); o[1] = (_Float16)(a.y * sc);
  o[2] = (_Float16)(a.z * sc); o[3] = (_Float16)(a.w * sc);
  o[4] = (_Float16)(b.x * sc); o[5] = (_Float16)(b.y * sc);
  o[6] = (_Float16)(b.z * sc); o[7] = (_Float16)(b.w * sc);
  return o;
}

// ---------------- fused prep: x cvt | weight cvt (+q scale) | edge count ----------------
__global__ void __launch_bounds__(256) prep_k(
    const float* __restrict__ x, const float* __restrict__ Wq,
    const float* __restrict__ Wk, const float* __restrict__ Wv,
    const float* __restrict__ Wo, const int* __restrict__ dst,
    _Float16* __restrict__ xh, _Float16* __restrict__ Wcat,
    _Float16* __restrict__ Woh, int* __restrict__ counts) {
  int b = blockIdx.x;
  int t = threadIdx.x;
  if (b < 1250) {
    int i = b * 256 + t;  // 320000 = 1250*256 exactly
    const float4* p = (const float4*)x;
    ((half8*)xh)[i] = cvt8s(p[2 * i], p[2 * i + 1], 1.0f);
  } else if (b < 1378) {
    int bb = b - 1250;
    int w = bb >> 5;                 // 0..3
    int i = (bb & 31) * 256 + t;     // 0..8191
    const float* in = (w == 0) ? Wq : (w == 1) ? Wv : (w == 2) ? Wk : Wo;
    _Float16* out = (w < 3) ? (Wcat + (size_t)w * 65536) : Woh;
    float sc = (w == 0) ? QK_SCALE : 1.0f;
    const float4* p = (const float4*)in;
    ((half8*)out)[i] = cvt8s(p[2 * i], p[2 * i + 1], sc);
  } else {
    int e = (b - 1378) * 256 + t;
    if (e < N_EDGES) atomicAdd(&counts[dst[e]], 1);
  }
}

// ---------------- DMA-staged fp16 MFMA GEMM: Y[M,N] = X[M,256] @ B[N,256]^T + bias --------
// BM=BN=128, BK=64, 256 threads = 4 waves, each wave 64x64 (4x4 MFMA frags).
// LDS K-major: [8 chunks][128 rows][8 halves]; DMA = wave-uniform base + lane*16B.
// MODE 0: dual fp16 dest (col<512 -> qv ld512; col>=512 -> kh ld256), bias = (bq*s|bv|bk).
// MODE 1: fp32 out ld256, bias = b0.
template <int MODE>
__global__ void __launch_bounds__(256) gemm_tiled(
    const _Float16* __restrict__ A, const _Float16* __restrict__ B,
    const float* __restrict__ b0, const float* __restrict__ b1,
    const float* __restrict__ b2,
    _Float16* __restrict__ qv, _Float16* __restrict__ kh,
    float* __restrict__ outf, int M) {
  __shared__ _Float16 As[8192];
  __shared__ _Float16 Bs[8192];
  int t = threadIdx.x;
  int lane = t & 63;
  int wid = t >> 6;
  int l16 = lane & 15;
  int quad = lane >> 4;
  int wm = wid >> 1, wn = wid & 1;
  int m0 = blockIdx.x * 128;
  int n0 = blockIdx.y * 128;

  floatx4 acc[4][4];
#pragma unroll
  for (int i = 0; i < 4; ++i)
#pragma unroll
    for (int j = 0; j < 4; ++j) acc[i][j] = (floatx4){0.f, 0.f, 0.f, 0.f};

  for (int ks = 0; ks < 4; ++ks) {
    if (ks) __syncthreads();
#pragma unroll
    for (int i = 0; i < 4; ++i) {
      int idx = i * 4 + wid;   // 0..15: chunk c = idx>>1, row-half h = idx&1
      int c = idx >> 1;
      int h = idx & 1;
      int r = h * 64 + lane;
      int ar = m0 + r;
      if (ar >= M) ar = M - 1;
      load16_lds(A + (size_t)ar * 256 + ks * 64 + c * 8, &As[(c * 128 + h * 64) * 8]);
      load16_lds(B + (size_t)(n0 + r) * 256 + ks * 64 + c * 8, &Bs[(c * 128 + h * 64) * 8]);
    }
    __syncthreads();
#pragma unroll
    for (int kk = 0; kk < 2; ++kk) {
      int j = kk * 4 + quad;
      half8 af[4], bf[4];
#pragma unroll
      for (int i = 0; i < 4; ++i) {
        af[i] = *(const half8*)&As[(j * 128 + wm * 64 + i * 16 + l16) * 8];
        bf[i] = *(const half8*)&Bs[(j * 128 + wn * 64 + i * 16 + l16) * 8];
      }
#pragma unroll
      for (int mi = 0; mi < 4; ++mi)
#pragma unroll
        for (int ni = 0; ni < 4; ++ni)
          acc[mi][ni] =
              __builtin_amdgcn_mfma_f32_16x16x32_f16(af[mi], bf[ni], acc[mi][ni], 0, 0, 0);
    }
  }

#pragma unroll
  for (int mi = 0; mi < 4; ++mi) {
#pragma unroll
    for (int ni = 0; ni < 4; ++ni) {
      int col = n0 + wn * 64 + ni * 16 + l16;
      float bias;
      if (MODE == 0) {
        bias = (col < 256) ? b0[col] * QK_SCALE
                           : (col < 512) ? b1[col - 256] : b2[col - 512];
      } else {
        bias = b0[col];
      }
#pragma unroll
      for (int r = 0; r < 4; ++r) {
        int row = m0 + wm * 64 + mi * 16 + quad * 4 + r;
        if (row < M) {
          float val = acc[mi][ni][r] + bias;
          if (MODE == 0) {
            if (col < 512)
              qv[(size_t)row * 512 + col] = (_Float16)val;
            else
              kh[(size_t)row * 256 + (col - 512)] = (_Float16)val;
          } else {
            outf[(size_t)row * 256 + col] = val;
          }
        }
      }
    }
  }
}

// ---------------- CSR scan + scatter ----------------
__global__ void scan_k(const int* __restrict__ counts, int* __restrict__ offs,
                       int* __restrict__ cursor) {
  __shared__ int ssum[256];
  int t = threadIdx.x;
  const int CH = 40;
  int begin = t * CH;
  int end = begin + CH;
  if (end > N_NODES) end = N_NODES;
  int s = 0;
  for (int i = begin; i < end; ++i) s += counts[i];
  ssum[t] = s;
  __syncthreads();
  if (t == 0) {
    int run = 0;
    for (int i = 0; i < 256; ++i) {
      int c = ssum[i];
      ssum[i] = run;
      run += c;
    }
    offs[N_NODES] = run;
  }
  __syncthreads();
  int run = ssum[t];
  for (int i = begin; i < end; ++i) {
    offs[i] = run;
    cursor[i] = run;
    run += counts[i];
  }
}

__global__ void scatter_k(const int* __restrict__ dst, const int* __restrict__ src,
                          int* __restrict__ cursor, int* __restrict__ slist) {
  int e = blockIdx.x * blockDim.x + threadIdx.x;
  if (e < N_EDGES) {
    int pos = atomicAdd(&cursor[dst[e]], 1);
    slist[pos] = src[e];
  }
}

// ---------------- fused score+softmax+aggregate (head-per-lane) ----------------
// One wave per node; 8 lanes per edge -> 8 edges per wave-iteration.
// Lane: h = lane&7 (head), g = lane>>3 (edge slot). Lane holds its head's full
// 32 dims of q,k,v -> QK dot fully in-lane via v_dot2_f32_f16 (no shuffles).
// Head softmax = 3 shfl_xor over lane bits 0..2. V-acc in packed fp16.
// No max-subtract (|score| ~ N(0,1), exp safe). q pre-scaled by 1/sqrt(32).
// qv rows are [q(256)|v(256)] contiguous 1KB.
__device__ __forceinline__ half2t h2shfl_xor(half2t x, int m) {
  union { half2t h; int i; } u; u.h = x;
  int r = __shfl_xor(u.i, m);
  union { int i; half2t h; } w; w.i = r;
  return w.h;
}

__device__ __forceinline__ float dot2(half2t a, half2t b, float c) {
#if __has_builtin(__builtin_amdgcn_fdot2)
  return __builtin_amdgcn_fdot2(a, b, c, false);
#else
  return c + (float)a[0] * (float)b[0] + (float)a[1] * (float)b[1];
#endif
}

__global__ void __launch_bounds__(128) aggregate_k(
    const _Float16* __restrict__ qv, const _Float16* __restrict__ kh,
    const int* __restrict__ slist, const int* __restrict__ offs,
    _Float16* __restrict__ hh) {
  int lane = threadIdx.x & 63;
  int n = blockIdx.x * 2 + (threadIdx.x >> 6);
  if (n >= N_NODES) return;
  int h = lane & 7;
  int g = lane >> 3;

  // this lane's head of k[n]: 32 halves = 4 half8
  half8 kc[4];
  const half8* krow = (const half8*)(kh + (size_t)n * DIM + h * 32);
#pragma unroll
  for (int i = 0; i < 4; ++i) kc[i] = krow[i];
  const half2t* k2 = (const half2t*)kc;

  half2t acc[16];
#pragma unroll
  for (int i = 0; i < 16; ++i) acc[i] = (half2t){(_Float16)0.f, (_Float16)0.f};

  int e0 = offs[n];
  int deg = offs[n + 1] - e0;

  for (int base = 0; base < deg; base += 64) {
    int nb = deg - base;
    if (nb > 64) nb = 64;
    int sid = 0;
    if (lane < nb) sid = slist[e0 + base + lane];
    int iters = (nb + 7) >> 3;

    // prefetch iteration 0
    int idx = g;
    int s = __shfl(sid, idx);
    const half8* r = (const half8*)(qv + (size_t)s * 512 + h * 32);
    half8 qc[4], vc[4];
#pragma unroll
    for (int i = 0; i < 4; ++i) { qc[i] = r[i]; vc[i] = r[32 + i]; }  // +32 half8 = +256 halves
    bool valid = idx < nb;

    for (int jj = 0; jj < iters; ++jj) {
      half8 nq[4], nv[4];
      bool nvalid = false;
      if (jj + 1 < iters) {
        int nidx = (jj + 1) * 8 + g;
        int ns = __shfl(sid, nidx);
        const half8* nr = (const half8*)(qv + (size_t)ns * 512 + h * 32);
#pragma unroll
        for (int i = 0; i < 4; ++i) { nq[i] = nr[i]; nv[i] = nr[32 + i]; }
        nvalid = nidx < nb;
      }
      // in-lane dot over 32 dims: 4 chains of 4 dot2
      const half2t* q2 = (const half2t*)qc;
      float pa = 0.f, pb = 0.f, pc = 0.f, pd = 0.f;
#pragma unroll
      for (int i = 0; i < 4; ++i) {
        pa = dot2(q2[i], k2[i], pa);
        pb = dot2(q2[4 + i], k2[4 + i], pb);
        pc = dot2(q2[8 + i], k2[8 + i], pc);
        pd = dot2(q2[12 + i], k2[12 + i], pd);
      }
      float p = (pa + pb) + (pc + pd);
      float ex = __expf(p);
      float ssum = ex;
      ssum += __shfl_xor(ssum, 1);
      ssum += __shfl_xor(ssum, 2);
      ssum += __shfl_xor(ssum, 4);
      float a = valid ? (ex * __frcp_rn(ssum)) : 0.f;
      _Float16 ah = (_Float16)a;
      half2t ah2 = (half2t){ah, ah};
      const half2t* v2 = (const half2t*)vc;
#pragma unroll
      for (int i = 0; i < 16; ++i) acc[i] += v2[i] * ah2;
#pragma unroll
      for (int i = 0; i < 4; ++i) { qc[i] = nq[i]; vc[i] = nv[i]; }
      valid = nvalid;
    }
  }

  // reduce across the 8 edge-groups (lane bits 3,4,5)
#pragma unroll
  for (int i = 0; i < 16; ++i) {
    acc[i] += h2shfl_xor(acc[i], 8);
    acc[i] += h2shfl_xor(acc[i], 16);
    acc[i] += h2shfl_xor(acc[i], 32);
  }
  if (g == 0) {
    half8* hrow = (half8*)(hh + (size_t)n * DIM + h * 32);
    const half8* a8 = (const half8*)acc;
#pragma unroll
    for (int i = 0; i < 4; ++i) hrow[i] = a8[i];
  }
}

// ---------------- launch ----------------
extern "C" void kernel_launch(void* const* d_in, const int* in_sizes, int n_in,
                              void* d_out, int out_size, void* d_ws, size_t ws_size,
                              hipStream_t stream) {
  const float* x = (const float*)d_in[0];
  const int* src = (const int*)d_in[1];
  const int* dst = (const int*)d_in[2];
  const float* Wq = (const float*)d_in[3];
  const float* bq = (const float*)d_in[4];
  const float* Wk = (const float*)d_in[5];
  const float* bk = (const float*)d_in[6];
  const float* Wv = (const float*)d_in[7];
  const float* bv = (const float*)d_in[8];
  const float* Wo = (const float*)d_in[9];
  const float* bo = (const float*)d_in[10];

  char* p = (char*)d_ws;
  const size_t SZ_NODE_H = (size_t)N_NODES * DIM * sizeof(_Float16);  // 5,120,000
  _Float16* xh = (_Float16*)p; p += SZ_NODE_H;
  _Float16* qvv = (_Float16*)p; p += 2 * SZ_NODE_H;  // [q|v] rows, 1KB each
  _Float16* kh = (_Float16*)p; p += SZ_NODE_H;
  _Float16* hh = (_Float16*)p; p += SZ_NODE_H;
  _Float16* Wcat = (_Float16*)p; p += (size_t)768 * 256 * sizeof(_Float16);
  _Float16* Woh = (_Float16*)p; p += (size_t)256 * 256 * sizeof(_Float16);
  int* counts = (int*)p; p += 40192;
  int* offs = (int*)p; p += 40192;
  int* cursor = (int*)p; p += 40192;
  int* slist = (int*)p; p += (size_t)N_EDGES * sizeof(int);

  hipMemsetAsync(counts, 0, N_NODES * sizeof(int), stream);

  prep_k<<<2628, 256, 0, stream>>>(x, Wq, Wk, Wv, Wo, dst, xh, Wcat, Woh, counts);

  gemm_tiled<0><<<dim3(79, 6), 256, 0, stream>>>(xh, Wcat, bq, bv, bk, qvv, kh,
                                                 nullptr, N_NODES);

  scan_k<<<1, 256, 0, stream>>>(counts, offs, cursor);
  scatter_k<<<(N_EDGES + 255) / 256, 256, 0, stream>>>(dst, src, cursor, slist);

  aggregate_k<<<(N_NODES + 1) / 2, 128, 0, stream>>>(qvv, kh, slist, offs, hh);

  gemm_tiled<1><<<dim3(79, 2), 256, 0, stream>>>(hh, Woh, bo, nullptr, nullptr,
                                                 nullptr, nullptr, (float*)d_out,
                                                 N_NODES);
}